// Round 3
// baseline (1124.684 us; speedup 1.0000x reference)
//
#include <hip/hip_runtime.h>
#include <hip/hip_bf16.h>

typedef __attribute__((ext_vector_type(8))) short bf16x8;
typedef __attribute__((ext_vector_type(4))) float f32x4;
typedef __attribute__((ext_vector_type(8))) _Float16 f16x8;
typedef __attribute__((ext_vector_type(8))) unsigned short u16x8;
typedef unsigned int uint32;
typedef unsigned short ushort;

#define MFMA16(a, b, c) __builtin_amdgcn_mfma_f32_16x16x32_bf16((a), (b), (c), 0, 0, 0)

__device__ __forceinline__ ushort f2bf(float f) {
    __hip_bfloat16 h = __float2bfloat16(f);
    return __builtin_bit_cast(ushort, h);
}
__device__ __forceinline__ float bf2f(ushort u) {
    uint32 v = ((uint32)u) << 16;
    return __builtin_bit_cast(float, v);
}

// ---------------------------------------------------------------------------
// Kernel 1a: transpose fp32 [C=256][N=4096] -> bf16 hi/lo [N][C]
// grid (N/64, C/64, 2*B), block 256
// ---------------------------------------------------------------------------
__global__ __launch_bounds__(256) void transpose_split(
    const float* __restrict__ Fc, const float* __restrict__ Fs,
    ushort* __restrict__ XcH, ushort* __restrict__ XcL,
    ushort* __restrict__ XsH, ushort* __restrict__ XsL) {
    __shared__ float lds[64][65];
    const int z = blockIdx.z;
    const int b = z & 3;
    const float* src = (z < 4) ? Fc : Fs;
    ushort* dh = (z < 4) ? XcH : XsH;
    ushort* dl = (z < 4) ? XcL : XsL;
    src += (size_t)b * 256 * 4096;
    dh += (size_t)b * 4096 * 256;
    dl += (size_t)b * 4096 * 256;
    const int i0 = blockIdx.x * 64;
    const int c0 = blockIdx.y * 64;
    const int col = threadIdx.x & 63;
    const int rb = threadIdx.x >> 6;  // 0..3
#pragma unroll
    for (int rr = 0; rr < 16; rr++) {
        int r = rb * 16 + rr;  // c-local
        lds[r][col] = src[(size_t)(c0 + r) * 4096 + i0 + col];
    }
    __syncthreads();
#pragma unroll
    for (int rr = 0; rr < 16; rr++) {
        int r = rb * 16 + rr;  // i-local
        float f = lds[col][r];
        ushort h = f2bf(f);
        dh[(size_t)(i0 + r) * 256 + c0 + col] = h;
        dl[(size_t)(i0 + r) * 256 + c0 + col] = f2bf(f - bf2f(h));
    }
}

// ---------------------------------------------------------------------------
// Kernel 1b: weights fp32 -> bf16; w_f scaled by log2e, w_f/w_g split hi/lo.
// grid 256, block 256
// ---------------------------------------------------------------------------
__global__ __launch_bounds__(256) void convert_weights(
    const float* __restrict__ wf, const float* __restrict__ wg,
    const float* __restrict__ wh, const float* __restrict__ wo,
    ushort* __restrict__ wfh, ushort* __restrict__ wfl,
    ushort* __restrict__ wgh, ushort* __restrict__ wgl,
    ushort* __restrict__ whb, ushort* __restrict__ wob) {
    const int t = blockIdx.x * 256 + threadIdx.x;  // 0..65535
    const float L2E = 1.4426950408889634f;
    float sf = wf[t] * L2E;
    ushort hf = f2bf(sf);
    wfh[t] = hf;
    wfl[t] = f2bf(sf - bf2f(hf));
    float sg = wg[t];
    ushort hg = f2bf(sg);
    wgh[t] = hg;
    wgl[t] = f2bf(sg - bf2f(hg));
    whb[t] = f2bf(wh[t]);
    wob[t] = f2bf(wo[t]);
}

// ---------------------------------------------------------------------------
// Kernel 2a: Q/K projection, split precision. NT GEMM, K=256.
// grid (256, 8), block 256 (4 waves, tile 64x64, wave = 16m x 64n)
// ---------------------------------------------------------------------------
__global__ __launch_bounds__(256) void proj_qk(
    const ushort* __restrict__ XcH, const ushort* __restrict__ XcL,
    const ushort* __restrict__ XsH, const ushort* __restrict__ XsL,
    const ushort* __restrict__ wfh, const ushort* __restrict__ wfl,
    const ushort* __restrict__ wgh, const ushort* __restrict__ wgl,
    const float* __restrict__ bf_, const float* __restrict__ bg_,
    ushort* __restrict__ QH, ushort* __restrict__ QL,
    ushort* __restrict__ KH, ushort* __restrict__ KL) {
    const int y = blockIdx.y;
    const int isK = y >> 2;
    const int b = y & 3;
    const size_t bNC = (size_t)b * 4096 * 256;
    const ushort* Ah = (isK ? XsH : XcH) + bNC;
    const ushort* Al = (isK ? XsL : XcL) + bNC;
    const ushort* Bh = isK ? wgh : wfh;
    const ushort* Bl = isK ? wgl : wfl;
    const float* bias = isK ? bg_ : bf_;
    const float bscale = isK ? 1.0f : 1.4426950408889634f;
    ushort* Ch = (isK ? KH : QH) + bNC;
    ushort* Cl = (isK ? KL : QL) + bNC;
    const int m0 = (blockIdx.x & 63) * 64, n0 = (blockIdx.x >> 6) * 64;
    const int l = threadIdx.x & 63, wv = threadIdx.x >> 6;
    const int g = l >> 4, l15 = l & 15;
    const int mrow = m0 + wv * 16 + l15;

    f32x4 acc[4] = {{0, 0, 0, 0}, {0, 0, 0, 0}, {0, 0, 0, 0}, {0, 0, 0, 0}};
#pragma unroll
    for (int kk = 0; kk < 8; kk++) {
        bf16x8 ah = *(const bf16x8*)(Ah + (size_t)mrow * 256 + kk * 32 + g * 8);
        bf16x8 al = *(const bf16x8*)(Al + (size_t)mrow * 256 + kk * 32 + g * 8);
#pragma unroll
        for (int nt = 0; nt < 4; nt++) {
            const size_t boff = (size_t)(n0 + nt * 16 + l15) * 256 + kk * 32 + g * 8;
            bf16x8 bh = *(const bf16x8*)(Bh + boff);
            bf16x8 bl = *(const bf16x8*)(Bl + boff);
            acc[nt] = MFMA16(ah, bh, acc[nt]);
            acc[nt] = MFMA16(ah, bl, acc[nt]);
            acc[nt] = MFMA16(al, bh, acc[nt]);
        }
    }
#pragma unroll
    for (int nt = 0; nt < 4; nt++) {
        float bn = bias[n0 + nt * 16 + l15] * bscale;
#pragma unroll
        for (int r = 0; r < 4; r++) {
            int mr = m0 + wv * 16 + g * 4 + r;
            float v = acc[nt][r] + bn;
            ushort h = f2bf(v);
            Ch[(size_t)mr * 256 + n0 + nt * 16 + l15] = h;
            Cl[(size_t)mr * 256 + n0 + nt * 16 + l15] = f2bf(v - bf2f(h));
        }
    }
}

// ---------------------------------------------------------------------------
// Kernel 2b: V projection. V[o,j] = wh[o,:]·Xs[j,:] + bh[o], ldc=4096.
// grid (256, 4), block 256
// ---------------------------------------------------------------------------
__global__ __launch_bounds__(256) void proj_v(
    const ushort* __restrict__ XsH, const ushort* __restrict__ whb,
    const float* __restrict__ bh_, ushort* __restrict__ Vv) {
    const int b = blockIdx.y;
    const size_t bNC = (size_t)b * 4096 * 256;
    const ushort* A = whb;
    const ushort* Bp = XsH + bNC;
    ushort* Cp = Vv + bNC;
    const int m0 = (blockIdx.x & 3) * 64, n0 = (blockIdx.x >> 2) * 64;
    const int l = threadIdx.x & 63, wv = threadIdx.x >> 6;
    const int g = l >> 4, l15 = l & 15;
    const int mrow = m0 + wv * 16 + l15;

    f32x4 acc[4] = {{0, 0, 0, 0}, {0, 0, 0, 0}, {0, 0, 0, 0}, {0, 0, 0, 0}};
#pragma unroll
    for (int kk = 0; kk < 8; kk++) {
        bf16x8 af = *(const bf16x8*)(A + (size_t)mrow * 256 + kk * 32 + g * 8);
#pragma unroll
        for (int nt = 0; nt < 4; nt++) {
            bf16x8 bfr = *(const bf16x8*)(Bp + (size_t)(n0 + nt * 16 + l15) * 256 + kk * 32 + g * 8);
            acc[nt] = MFMA16(af, bfr, acc[nt]);
        }
    }
#pragma unroll
    for (int nt = 0; nt < 4; nt++) {
#pragma unroll
        for (int r = 0; r < 4; r++) {
            int mr = m0 + wv * 16 + g * 4 + r;
            Cp[(size_t)mr * 4096 + n0 + nt * 16 + l15] = f2bf(acc[nt][r] + bh_[mr]);
        }
    }
}

// ---------------------------------------------------------------------------
// Kernel 3: flash attention with KV-split (S=4 splits of 1024 keys).
// 1-D grid of 1024 blocks, XCD-swizzled so each XCD's L2 holds 2 (b,split)
// K/V groups (~3 MB). block 256 (4 waves x 16 queries).
// Swapped QK^T: S^T = mfma(K, Q), 3-term hi/lo in 6 independent chains.
// Outputs: Opart[s][b][i][c] fp16 (locally-normalized O), ML[s][b][i] = (M,L).
// ---------------------------------------------------------------------------
__global__ __launch_bounds__(256) void attn_split(
    const ushort* __restrict__ QH, const ushort* __restrict__ QL,
    const ushort* __restrict__ KH, const ushort* __restrict__ KL,
    const ushort* __restrict__ Vv, _Float16* __restrict__ Opart,
    float2* __restrict__ ML) {
    // swizzle: consecutive hardware ids round-robin XCDs; give each XCD
    // two (b,split) groups so K/V stay L2-resident.
    const int h = blockIdx.x;
    const int xcd = h & 7;
    const int j = h >> 3;
    const int grp = xcd + 8 * (j & 1);  // 0..15 = (b,s)
    const int itile = j >> 1;           // 0..63
    const int b = grp >> 2;
    const int s = grp & 3;

    const int l = threadIdx.x & 63, wv = threadIdx.x >> 6;
    const int g = l >> 4, l15 = l & 15;
    const int iw = itile * 64 + wv * 16;
    const ushort* QHb = QH + ((size_t)b * 4096 + iw) * 256;
    const ushort* QLb = QL + ((size_t)b * 4096 + iw) * 256;
    const ushort* KHb = KH + (size_t)b * 4096 * 256;
    const ushort* KLb = KL + (size_t)b * 4096 * 256;
    const ushort* Vb = Vv + (size_t)b * 4096 * 256;  // [256][4096]

    bf16x8 qh[8], ql[8];
#pragma unroll
    for (int kk = 0; kk < 8; kk++) {
        qh[kk] = *(const bf16x8*)(QHb + (size_t)l15 * 256 + kk * 32 + g * 8);
        ql[kk] = *(const bf16x8*)(QLb + (size_t)l15 * 256 + kk * 32 + g * 8);
    }

    f32x4 acc[16];
#pragma unroll
    for (int ct = 0; ct < 16; ct++) acc[ct] = (f32x4){0, 0, 0, 0};
    float M = -INFINITY, Lsum = 0.0f;

    const int jbeg = s * 1024, jend = jbeg + 1024;
    for (int j0 = jbeg; j0 < jend; j0 += 32) {
        f32x4 s0a = {0, 0, 0, 0}, s0b = {0, 0, 0, 0}, s0c = {0, 0, 0, 0};
        f32x4 s1a = {0, 0, 0, 0}, s1b = {0, 0, 0, 0}, s1c = {0, 0, 0, 0};
#pragma unroll
        for (int kk = 0; kk < 8; kk++) {
            const size_t o0 = (size_t)(j0 + l15) * 256 + kk * 32 + g * 8;
            const size_t o1 = (size_t)(j0 + 16 + l15) * 256 + kk * 32 + g * 8;
            bf16x8 kh0 = *(const bf16x8*)(KHb + o0);
            bf16x8 kh1 = *(const bf16x8*)(KHb + o1);
            bf16x8 kl0 = *(const bf16x8*)(KLb + o0);
            bf16x8 kl1 = *(const bf16x8*)(KLb + o1);
            s0a = MFMA16(kh0, qh[kk], s0a);
            s0b = MFMA16(kh0, ql[kk], s0b);
            s0c = MFMA16(kl0, qh[kk], s0c);
            s1a = MFMA16(kh1, qh[kk], s1a);
            s1b = MFMA16(kh1, ql[kk], s1b);
            s1c = MFMA16(kl1, qh[kk], s1c);
        }
        f32x4 s0 = (s0a + s0b) + s0c;
        f32x4 s1 = (s1a + s1b) + s1c;
        // lane holds S^T: query i = iw+l15; j = j0 + 16*t + g*4 + r
        float tm = fmaxf(fmaxf(fmaxf(s0[0], s0[1]), fmaxf(s0[2], s0[3])),
                         fmaxf(fmaxf(s1[0], s1[1]), fmaxf(s1[2], s1[3])));
        tm = fmaxf(tm, __shfl_xor(tm, 16));
        tm = fmaxf(tm, __shfl_xor(tm, 32));
        float newM = fmaxf(M, tm);
        if (__any(newM > M)) {
            float alpha = exp2f(M - newM);  // 1 if unchanged; 0 on first tile
            Lsum *= alpha;
            float ar[4];
#pragma unroll
            for (int r = 0; r < 4; r++) ar[r] = __shfl(alpha, g * 4 + r);
#pragma unroll
            for (int ct = 0; ct < 16; ct++) {
#pragma unroll
                for (int r = 0; r < 4; r++) acc[ct][r] *= ar[r];
            }
        }
        M = newM;
        float p[8];
#pragma unroll
        for (int r = 0; r < 4; r++) {
            p[r] = exp2f(s0[r] - M);
            p[4 + r] = exp2f(s1[r] - M);
        }
        Lsum += p[0] + p[1] + p[2] + p[3] + p[4] + p[5] + p[6] + p[7];

        uint32 pk[4];
        pk[0] = (uint32)f2bf(p[0]) | ((uint32)f2bf(p[1]) << 16);  // s0, j+{0,1}
        pk[1] = (uint32)f2bf(p[2]) | ((uint32)f2bf(p[3]) << 16);  // s0, j+{2,3}
        pk[2] = (uint32)f2bf(p[4]) | ((uint32)f2bf(p[5]) << 16);  // s1, j+{0,1}
        pk[3] = (uint32)f2bf(p[6]) | ((uint32)f2bf(p[7]) << 16);  // s1, j+{2,3}
        // gather PV A-fragment: lane (g,l15) needs P[i=l15][j = j0 + g*8 + 0..7]
        const int ts = g >> 1;
        const int s1l = l15 + ((g & 1) << 5);
        uint32 w0a = __shfl(pk[0], s1l), w0b = __shfl(pk[2], s1l);
        uint32 w1a = __shfl(pk[1], s1l), w1b = __shfl(pk[3], s1l);
        uint32 w2a = __shfl(pk[0], s1l + 16), w2b = __shfl(pk[2], s1l + 16);
        uint32 w3a = __shfl(pk[1], s1l + 16), w3b = __shfl(pk[3], s1l + 16);
        union { uint32 u[4]; bf16x8 v; } pun;
        pun.u[0] = ts ? w0b : w0a;
        pun.u[1] = ts ? w1b : w1a;
        pun.u[2] = ts ? w2b : w2a;
        pun.u[3] = ts ? w3b : w3a;
        bf16x8 pf = pun.v;

#pragma unroll
        for (int ct = 0; ct < 16; ct++) {
            bf16x8 vf = *(const bf16x8*)(Vb + (size_t)(ct * 16 + l15) * 4096 + j0 + g * 8);
            acc[ct] = MFMA16(pf, vf, acc[ct]);
        }
    }
    float Lt = Lsum + __shfl_xor(Lsum, 16);
    Lt += __shfl_xor(Lt, 32);
    float inv = 1.0f / Lt;
    float ivr[4];
#pragma unroll
    for (int r = 0; r < 4; r++) ivr[r] = __shfl(inv, g * 4 + r);
    const size_t sb = (size_t)(s * 4 + b);
    _Float16* Ob = Opart + (sb * 4096 + iw) * 256;
#pragma unroll
    for (int ct = 0; ct < 16; ct++) {
#pragma unroll
        for (int r = 0; r < 4; r++)
            Ob[(size_t)(g * 4 + r) * 256 + ct * 16 + l15] =
                (_Float16)(acc[ct][r] * ivr[r]);
    }
    if (g == 0) {
        float2 ml;
        ml.x = M;
        ml.y = Lt;
        ML[sb * 4096 + iw + l15] = ml;
    }
}

// ---------------------------------------------------------------------------
// Kernel 3b: combine splits. O = sum_s w_s O_s, w_s = L_s*2^(M_s-Mmax)/denom.
// grid (512, 4), block 256: 8 rows/block, 32 threads/row x 8 c each.
// ---------------------------------------------------------------------------
__global__ __launch_bounds__(256) void attn_combine(
    const _Float16* __restrict__ Opart, const float2* __restrict__ ML,
    ushort* __restrict__ Rt) {
    const int b = blockIdx.y;
    const int i = blockIdx.x * 8 + (threadIdx.x >> 5);
    const int c0 = (threadIdx.x & 31) * 8;
    float m[4], lv[4];
#pragma unroll
    for (int s = 0; s < 4; s++) {
        float2 ml = ML[(size_t)(s * 4 + b) * 4096 + i];
        m[s] = ml.x;
        lv[s] = ml.y;
    }
    float Mmax = fmaxf(fmaxf(m[0], m[1]), fmaxf(m[2], m[3]));
    float w[4], denom = 0.0f;
#pragma unroll
    for (int s = 0; s < 4; s++) {
        w[s] = lv[s] * exp2f(m[s] - Mmax);
        denom += w[s];
    }
    float inv = 1.0f / denom;
    float o[8] = {0, 0, 0, 0, 0, 0, 0, 0};
#pragma unroll
    for (int s = 0; s < 4; s++) {
        float ws = w[s] * inv;
        f16x8 v = *(const f16x8*)(Opart + ((size_t)(s * 4 + b) * 4096 + i) * 256 + c0);
#pragma unroll
        for (int e = 0; e < 8; e++) o[e] += ws * (float)v[e];
    }
    u16x8 r;
#pragma unroll
    for (int e = 0; e < 8; e++) r[e] = f2bf(o[e]);
    *(u16x8*)(Rt + ((size_t)b * 4096 + i) * 256 + c0) = r;
}

// ---------------------------------------------------------------------------
// Kernel 4: out[o,i] = wo[o,:]·Rt[i,:] + bo[o], fp32 out [C][N].
// grid (256, B), block 256
// ---------------------------------------------------------------------------
__global__ __launch_bounds__(256) void out_proj(
    const ushort* __restrict__ wob, const ushort* __restrict__ Rt,
    const float* __restrict__ bo, float* __restrict__ Out) {
    const int b = blockIdx.y;
    const int m0 = (blockIdx.x & 3) * 64;
    const int n0 = (blockIdx.x >> 2) * 64;
    const int l = threadIdx.x & 63, wv = threadIdx.x >> 6;
    const int g = l >> 4, l15 = l & 15;
    const ushort* Bp = Rt + (size_t)b * 4096 * 256;
    float* Ob = Out + (size_t)b * 256 * 4096;
    const int mrow = m0 + wv * 16 + l15;

    f32x4 acc[4] = {{0, 0, 0, 0}, {0, 0, 0, 0}, {0, 0, 0, 0}, {0, 0, 0, 0}};
#pragma unroll
    for (int kk = 0; kk < 8; kk++) {
        bf16x8 af = *(const bf16x8*)(wob + (size_t)mrow * 256 + kk * 32 + g * 8);
#pragma unroll
        for (int nt = 0; nt < 4; nt++) {
            bf16x8 bfr = *(const bf16x8*)(Bp + (size_t)(n0 + nt * 16 + l15) * 256 + kk * 32 + g * 8);
            acc[nt] = MFMA16(af, bfr, acc[nt]);
        }
    }
#pragma unroll
    for (int nt = 0; nt < 4; nt++) {
#pragma unroll
        for (int r = 0; r < 4; r++) {
            int mr = m0 + wv * 16 + g * 4 + r;
            Ob[(size_t)mr * 4096 + n0 + nt * 16 + l15] = acc[nt][r] + bo[mr];
        }
    }
}

// ---------------------------------------------------------------------------
extern "C" void kernel_launch(void* const* d_in, const int* in_sizes, int n_in,
                              void* d_out, int out_size, void* d_ws, size_t ws_size,
                              hipStream_t stream) {
    const float* Fc = (const float*)d_in[0];
    const float* Fs = (const float*)d_in[1];
    const float* wf = (const float*)d_in[2];
    const float* bf_ = (const float*)d_in[3];
    const float* wg = (const float*)d_in[4];
    const float* bg = (const float*)d_in[5];
    const float* wh = (const float*)d_in[6];
    const float* bh = (const float*)d_in[7];
    const float* wo = (const float*)d_in[8];
    const float* bo = (const float*)d_in[9];
    float* Out = (float*)d_out;

    char* ws = (char*)d_ws;
    const size_t SZ = (size_t)4 * 4096 * 256 * 2;  // 8 MB per [B][4096][256] bf16
    ushort* QHp = (ushort*)(ws + 0 * SZ);
    ushort* QLp = (ushort*)(ws + 1 * SZ);
    ushort* KHp = (ushort*)(ws + 2 * SZ);
    ushort* KLp = (ushort*)(ws + 3 * SZ);
    ushort* Vv  = (ushort*)(ws + 4 * SZ);
    ushort* XcH = (ushort*)(ws + 5 * SZ);
    ushort* XcL = (ushort*)(ws + 6 * SZ);
    ushort* XsH = (ushort*)(ws + 7 * SZ);
    ushort* XsL = (ushort*)(ws + 8 * SZ);
    // Opart aliases XcH..XsL (dead after projections): 4 splits x 8 MB fp16
    _Float16* Opart = (_Float16*)(ws + 5 * SZ);
    char* wsw = ws + 9 * SZ;
    ushort* wfh = (ushort*)(wsw + 0 * 131072);
    ushort* wfl = (ushort*)(wsw + 1 * 131072);
    ushort* wgh = (ushort*)(wsw + 2 * 131072);
    ushort* wgl = (ushort*)(wsw + 3 * 131072);
    ushort* whb = (ushort*)(wsw + 4 * 131072);
    ushort* wob = (ushort*)(wsw + 5 * 131072);
    float2* ML = (float2*)(wsw + 6 * 131072);  // 4*4*4096*8 = 512 KB
    ushort* Rt = QHp;  // alias: Q dead once attn_split completes

    transpose_split<<<dim3(64, 4, 8), 256, 0, stream>>>(Fc, Fs, XcH, XcL, XsH, XsL);
    convert_weights<<<dim3(256), 256, 0, stream>>>(wf, wg, wh, wo, wfh, wfl, wgh, wgl, whb, wob);
    proj_qk<<<dim3(256, 8), 256, 0, stream>>>(XcH, XcL, XsH, XsL, wfh, wfl, wgh, wgl,
                                              bf_, bg, QHp, QLp, KHp, KLp);
    proj_v<<<dim3(256, 4), 256, 0, stream>>>(XsH, whb, bh, Vv);
    attn_split<<<dim3(1024), 256, 0, stream>>>(QHp, QLp, KHp, KLp, Vv, Opart, ML);
    attn_combine<<<dim3(512, 4), 256, 0, stream>>>(Opart, ML, Rt);
    out_proj<<<dim3(256, 4), 256, 0, stream>>>(wob, Rt, bo, Out);
}

// Round 4
// 408.691 us; speedup vs baseline: 2.7519x; 2.7519x over previous
//
#include <hip/hip_runtime.h>
#include <hip/hip_bf16.h>

typedef __attribute__((ext_vector_type(8))) short bf16x8;
typedef __attribute__((ext_vector_type(4))) float f32x4;
typedef __attribute__((ext_vector_type(8))) _Float16 f16x8;
typedef __attribute__((ext_vector_type(8))) unsigned short u16x8;
typedef unsigned int uint32;
typedef unsigned short ushort;

#define MFMA16(a, b, c) __builtin_amdgcn_mfma_f32_16x16x32_bf16((a), (b), (c), 0, 0, 0)

__device__ __forceinline__ ushort f2bf(float f) {
    __hip_bfloat16 h = __float2bfloat16(f);
    return __builtin_bit_cast(ushort, h);
}
__device__ __forceinline__ float bf2f(ushort u) {
    uint32 v = ((uint32)u) << 16;
    return __builtin_bit_cast(float, v);
}
// async global->LDS, 16B per lane; lds dest = uniform base + lane*16
__device__ __forceinline__ void gld16(const ushort* g, ushort* l) {
    __builtin_amdgcn_global_load_lds(
        (const __attribute__((address_space(1))) unsigned int*)g,
        (__attribute__((address_space(3))) unsigned int*)l, 16, 0, 0);
}

// ---------------------------------------------------------------------------
// Kernel 1a: transpose fp32 [C=256][N=4096] -> bf16 hi/lo [N][C]
// grid (N/64, C/64, 2*B), block 256
// ---------------------------------------------------------------------------
__global__ __launch_bounds__(256) void transpose_split(
    const float* __restrict__ Fc, const float* __restrict__ Fs,
    ushort* __restrict__ XcH, ushort* __restrict__ XcL,
    ushort* __restrict__ XsH, ushort* __restrict__ XsL) {
    __shared__ float lds[64][65];
    const int z = blockIdx.z;
    const int b = z & 3;
    const float* src = (z < 4) ? Fc : Fs;
    ushort* dh = (z < 4) ? XcH : XsH;
    ushort* dl = (z < 4) ? XcL : XsL;
    src += (size_t)b * 256 * 4096;
    dh += (size_t)b * 4096 * 256;
    dl += (size_t)b * 4096 * 256;
    const int i0 = blockIdx.x * 64;
    const int c0 = blockIdx.y * 64;
    const int col = threadIdx.x & 63;
    const int rb = threadIdx.x >> 6;  // 0..3
#pragma unroll
    for (int rr = 0; rr < 16; rr++) {
        int r = rb * 16 + rr;  // c-local
        lds[r][col] = src[(size_t)(c0 + r) * 4096 + i0 + col];
    }
    __syncthreads();
#pragma unroll
    for (int rr = 0; rr < 16; rr++) {
        int r = rb * 16 + rr;  // i-local
        float f = lds[col][r];
        ushort h = f2bf(f);
        dh[(size_t)(i0 + r) * 256 + c0 + col] = h;
        dl[(size_t)(i0 + r) * 256 + c0 + col] = f2bf(f - bf2f(h));
    }
}

// ---------------------------------------------------------------------------
// Kernel 1b: weights fp32 -> bf16; w_f scaled by log2e, w_f/w_g split hi/lo.
// grid 256, block 256
// ---------------------------------------------------------------------------
__global__ __launch_bounds__(256) void convert_weights(
    const float* __restrict__ wf, const float* __restrict__ wg,
    const float* __restrict__ wh, const float* __restrict__ wo,
    ushort* __restrict__ wfh, ushort* __restrict__ wfl,
    ushort* __restrict__ wgh, ushort* __restrict__ wgl,
    ushort* __restrict__ whb, ushort* __restrict__ wob) {
    const int t = blockIdx.x * 256 + threadIdx.x;  // 0..65535
    const float L2E = 1.4426950408889634f;
    float sf = wf[t] * L2E;
    ushort hf = f2bf(sf);
    wfh[t] = hf;
    wfl[t] = f2bf(sf - bf2f(hf));
    float sg = wg[t];
    ushort hg = f2bf(sg);
    wgh[t] = hg;
    wgl[t] = f2bf(sg - bf2f(hg));
    whb[t] = f2bf(wh[t]);
    wob[t] = f2bf(wo[t]);
}

// ---------------------------------------------------------------------------
// Kernel 2a: Q/K projection, split precision. NT GEMM, K=256.
// grid (256, 8), block 256 (4 waves, tile 64x64, wave = 16m x 64n)
// ---------------------------------------------------------------------------
__global__ __launch_bounds__(256) void proj_qk(
    const ushort* __restrict__ XcH, const ushort* __restrict__ XcL,
    const ushort* __restrict__ XsH, const ushort* __restrict__ XsL,
    const ushort* __restrict__ wfh, const ushort* __restrict__ wfl,
    const ushort* __restrict__ wgh, const ushort* __restrict__ wgl,
    const float* __restrict__ bf_, const float* __restrict__ bg_,
    ushort* __restrict__ QH, ushort* __restrict__ QL,
    ushort* __restrict__ KH, ushort* __restrict__ KL) {
    const int y = blockIdx.y;
    const int isK = y >> 2;
    const int b = y & 3;
    const size_t bNC = (size_t)b * 4096 * 256;
    const ushort* Ah = (isK ? XsH : XcH) + bNC;
    const ushort* Al = (isK ? XsL : XcL) + bNC;
    const ushort* Bh = isK ? wgh : wfh;
    const ushort* Bl = isK ? wgl : wfl;
    const float* bias = isK ? bg_ : bf_;
    const float bscale = isK ? 1.0f : 1.4426950408889634f;
    ushort* Ch = (isK ? KH : QH) + bNC;
    ushort* Cl = (isK ? KL : QL) + bNC;
    const int m0 = (blockIdx.x & 63) * 64, n0 = (blockIdx.x >> 6) * 64;
    const int l = threadIdx.x & 63, wv = threadIdx.x >> 6;
    const int g = l >> 4, l15 = l & 15;
    const int mrow = m0 + wv * 16 + l15;

    f32x4 acc[4] = {{0, 0, 0, 0}, {0, 0, 0, 0}, {0, 0, 0, 0}, {0, 0, 0, 0}};
#pragma unroll
    for (int kk = 0; kk < 8; kk++) {
        bf16x8 ah = *(const bf16x8*)(Ah + (size_t)mrow * 256 + kk * 32 + g * 8);
        bf16x8 al = *(const bf16x8*)(Al + (size_t)mrow * 256 + kk * 32 + g * 8);
#pragma unroll
        for (int nt = 0; nt < 4; nt++) {
            const size_t boff = (size_t)(n0 + nt * 16 + l15) * 256 + kk * 32 + g * 8;
            bf16x8 bh = *(const bf16x8*)(Bh + boff);
            bf16x8 bl = *(const bf16x8*)(Bl + boff);
            acc[nt] = MFMA16(ah, bh, acc[nt]);
            acc[nt] = MFMA16(ah, bl, acc[nt]);
            acc[nt] = MFMA16(al, bh, acc[nt]);
        }
    }
#pragma unroll
    for (int nt = 0; nt < 4; nt++) {
        float bn = bias[n0 + nt * 16 + l15] * bscale;
#pragma unroll
        for (int r = 0; r < 4; r++) {
            int mr = m0 + wv * 16 + g * 4 + r;
            float v = acc[nt][r] + bn;
            ushort h = f2bf(v);
            Ch[(size_t)mr * 256 + n0 + nt * 16 + l15] = h;
            Cl[(size_t)mr * 256 + n0 + nt * 16 + l15] = f2bf(v - bf2f(h));
        }
    }
}

// ---------------------------------------------------------------------------
// Kernel 2b: V projection. V[o,j] = wh[o,:]·Xs[j,:] + bh[o], ldc=4096.
// grid (256, 4), block 256
// ---------------------------------------------------------------------------
__global__ __launch_bounds__(256) void proj_v(
    const ushort* __restrict__ XsH, const ushort* __restrict__ whb,
    const float* __restrict__ bh_, ushort* __restrict__ Vv) {
    const int b = blockIdx.y;
    const size_t bNC = (size_t)b * 4096 * 256;
    const ushort* A = whb;
    const ushort* Bp = XsH + bNC;
    ushort* Cp = Vv + bNC;
    const int m0 = (blockIdx.x & 3) * 64, n0 = (blockIdx.x >> 2) * 64;
    const int l = threadIdx.x & 63, wv = threadIdx.x >> 6;
    const int g = l >> 4, l15 = l & 15;
    const int mrow = m0 + wv * 16 + l15;

    f32x4 acc[4] = {{0, 0, 0, 0}, {0, 0, 0, 0}, {0, 0, 0, 0}, {0, 0, 0, 0}};
#pragma unroll
    for (int kk = 0; kk < 8; kk++) {
        bf16x8 af = *(const bf16x8*)(A + (size_t)mrow * 256 + kk * 32 + g * 8);
#pragma unroll
        for (int nt = 0; nt < 4; nt++) {
            bf16x8 bfr = *(const bf16x8*)(Bp + (size_t)(n0 + nt * 16 + l15) * 256 + kk * 32 + g * 8);
            acc[nt] = MFMA16(af, bfr, acc[nt]);
        }
    }
#pragma unroll
    for (int nt = 0; nt < 4; nt++) {
#pragma unroll
        for (int r = 0; r < 4; r++) {
            int mr = m0 + wv * 16 + g * 4 + r;
            Cp[(size_t)mr * 4096 + n0 + nt * 16 + l15] = f2bf(acc[nt][r] + bh_[mr]);
        }
    }
}

// ---------------------------------------------------------------------------
// Kernel 3: flash attention, KV-split S=4, LDS-staged K/V shared by 8 waves.
// grid 512 blocks (16 (b,s)-groups x 32 q-tiles), block 512 = 8 waves x 16 q.
// Per 32-key tile: stage Khi/Klo (XOR-swizzled via pre-swizzled global src)
// + V^T tile into LDS via global_load_lds(16B); all waves consume from LDS.
// __launch_bounds__(512,2) -> <=256 regs/wave -> 2 waves/SIMD.
// ---------------------------------------------------------------------------
__global__ __launch_bounds__(512, 2) void attn_split(
    const ushort* __restrict__ QH, const ushort* __restrict__ QL,
    const ushort* __restrict__ KH, const ushort* __restrict__ KL,
    const ushort* __restrict__ Vv, _Float16* __restrict__ Opart,
    float2* __restrict__ ML) {
    __shared__ __align__(16) ushort Khi[32 * 256];  // 16KB, col-slot ^= row
    __shared__ __align__(16) ushort Klo[32 * 256];  // 16KB
    __shared__ __align__(16) ushort Vt[256 * 32];   // 16KB, [ch][key] linear

    const int h = blockIdx.x;
    const int xcd = h & 7;
    const int j = h >> 3;
    const int grp = xcd + 8 * (j & 1);  // 0..15 = (b,s)
    const int itile = j >> 1;           // 0..31
    const int b = grp >> 2;
    const int s = grp & 3;

    const int l = threadIdx.x & 63, wv = threadIdx.x >> 6;  // wv 0..7
    const int g = l >> 4, l15 = l & 15;
    const int iw = itile * 128 + wv * 16;
    const ushort* QHb = QH + ((size_t)b * 4096 + iw) * 256;
    const ushort* QLb = QL + ((size_t)b * 4096 + iw) * 256;
    const ushort* KHb = KH + (size_t)b * 4096 * 256;
    const ushort* KLb = KL + (size_t)b * 4096 * 256;
    const ushort* Vb = Vv + (size_t)b * 4096 * 256;  // [256][4096]

    bf16x8 qh[8], ql[8];
#pragma unroll
    for (int kk = 0; kk < 8; kk++) {
        qh[kk] = *(const bf16x8*)(QHb + (size_t)l15 * 256 + kk * 32 + g * 8);
        ql[kk] = *(const bf16x8*)(QLb + (size_t)l15 * 256 + kk * 32 + g * 8);
    }

    f32x4 acc[16];
#pragma unroll
    for (int ct = 0; ct < 16; ct++) acc[ct] = (f32x4){0, 0, 0, 0};
    float M = -INFINITY, Lsum = 0.0f;

    const int r0 = l15, r1 = l15 + 16;
    const int jbeg = s * 1024, jend = jbeg + 1024;
    for (int j0 = jbeg; j0 < jend; j0 += 32) {
        // ---- stage K/V tile into LDS (6 x 1KB DMA per wave) ----
        {
            const ushort* khs = KHb + (size_t)j0 * 256;
            const ushort* kls = KLb + (size_t)j0 * 256;
#pragma unroll
            for (int q = 0; q < 2; q++) {
                int issue = wv * 2 + q;          // 0..15
                int row = issue * 2 + (l >> 5);  // 0..31
                int scol = (((l & 31) ^ row) & 31) * 8;  // pre-swizzled source
                gld16(khs + (size_t)row * 256 + scol, &Khi[issue * 512]);
                gld16(kls + (size_t)row * 256 + scol, &Klo[issue * 512]);
                int ch = issue * 16 + (l >> 2);  // 0..255
                gld16(Vb + (size_t)ch * 4096 + j0 + (l & 3) * 8, &Vt[issue * 512]);
            }
        }
        asm volatile("s_waitcnt vmcnt(0)" ::: "memory");
        __syncthreads();

        // ---- QK^T (3-term hi/lo, 6 independent chains) ----
        f32x4 s0a = {0, 0, 0, 0}, s0b = {0, 0, 0, 0}, s0c = {0, 0, 0, 0};
        f32x4 s1a = {0, 0, 0, 0}, s1b = {0, 0, 0, 0}, s1c = {0, 0, 0, 0};
#pragma unroll
        for (int kk = 0; kk < 8; kk++) {
            const int cs = kk * 4 + g;
            bf16x8 kh0 = *(const bf16x8*)&Khi[r0 * 256 + ((cs ^ r0) & 31) * 8];
            bf16x8 kl0 = *(const bf16x8*)&Klo[r0 * 256 + ((cs ^ r0) & 31) * 8];
            bf16x8 kh1 = *(const bf16x8*)&Khi[r1 * 256 + ((cs ^ r1) & 31) * 8];
            bf16x8 kl1 = *(const bf16x8*)&Klo[r1 * 256 + ((cs ^ r1) & 31) * 8];
            s0a = MFMA16(kh0, qh[kk], s0a);
            s0b = MFMA16(kh0, ql[kk], s0b);
            s0c = MFMA16(kl0, qh[kk], s0c);
            s1a = MFMA16(kh1, qh[kk], s1a);
            s1b = MFMA16(kh1, ql[kk], s1b);
            s1c = MFMA16(kl1, qh[kk], s1c);
        }
        f32x4 s0 = (s0a + s0b) + s0c;
        f32x4 s1 = (s1a + s1b) + s1c;
        // lane holds S^T: query i = iw+l15; j = j0 + 16*t + g*4 + r
        float tm = fmaxf(fmaxf(fmaxf(s0[0], s0[1]), fmaxf(s0[2], s0[3])),
                         fmaxf(fmaxf(s1[0], s1[1]), fmaxf(s1[2], s1[3])));
        tm = fmaxf(tm, __shfl_xor(tm, 16));
        tm = fmaxf(tm, __shfl_xor(tm, 32));
        float newM = fmaxf(M, tm);
        if (__any(newM > M)) {
            float alpha = exp2f(M - newM);  // 1 if unchanged; 0 on first tile
            Lsum *= alpha;
            float ar[4];
#pragma unroll
            for (int r = 0; r < 4; r++) ar[r] = __shfl(alpha, g * 4 + r);
#pragma unroll
            for (int ct = 0; ct < 16; ct++) {
#pragma unroll
                for (int r = 0; r < 4; r++) acc[ct][r] *= ar[r];
            }
        }
        M = newM;
        float p[8];
#pragma unroll
        for (int r = 0; r < 4; r++) {
            p[r] = exp2f(s0[r] - M);
            p[4 + r] = exp2f(s1[r] - M);
        }
        Lsum += p[0] + p[1] + p[2] + p[3] + p[4] + p[5] + p[6] + p[7];

        uint32 pk[4];
        pk[0] = (uint32)f2bf(p[0]) | ((uint32)f2bf(p[1]) << 16);  // s0, j+{0,1}
        pk[1] = (uint32)f2bf(p[2]) | ((uint32)f2bf(p[3]) << 16);  // s0, j+{2,3}
        pk[2] = (uint32)f2bf(p[4]) | ((uint32)f2bf(p[5]) << 16);  // s1, j+{0,1}
        pk[3] = (uint32)f2bf(p[6]) | ((uint32)f2bf(p[7]) << 16);  // s1, j+{2,3}
        // gather PV A-fragment: lane (g,l15) needs P[i=l15][j = j0 + g*8 + 0..7]
        const int ts = g >> 1;
        const int s1l = l15 + ((g & 1) << 5);
        uint32 w0a = __shfl(pk[0], s1l), w0b = __shfl(pk[2], s1l);
        uint32 w1a = __shfl(pk[1], s1l), w1b = __shfl(pk[3], s1l);
        uint32 w2a = __shfl(pk[0], s1l + 16), w2b = __shfl(pk[2], s1l + 16);
        uint32 w3a = __shfl(pk[1], s1l + 16), w3b = __shfl(pk[3], s1l + 16);
        union { uint32 u[4]; bf16x8 v; } pun;
        pun.u[0] = ts ? w0b : w0a;
        pun.u[1] = ts ? w1b : w1a;
        pun.u[2] = ts ? w2b : w2a;
        pun.u[3] = ts ? w3b : w3a;
        bf16x8 pf = pun.v;

        // ---- PV from LDS V^T tile ----
#pragma unroll
        for (int ct = 0; ct < 16; ct++) {
            bf16x8 vf = *(const bf16x8*)&Vt[(ct * 16 + l15) * 32 + g * 8];
            acc[ct] = MFMA16(pf, vf, acc[ct]);
        }
        __syncthreads();  // all reads done before next tile's staging
    }
    float Lt = Lsum + __shfl_xor(Lsum, 16);
    Lt += __shfl_xor(Lt, 32);
    float inv = 1.0f / Lt;
    float ivr[4];
#pragma unroll
    for (int r = 0; r < 4; r++) ivr[r] = __shfl(inv, g * 4 + r);
    const size_t sb = (size_t)(s * 4 + b);
    _Float16* Ob = Opart + (sb * 4096 + iw) * 256;
#pragma unroll
    for (int ct = 0; ct < 16; ct++) {
#pragma unroll
        for (int r = 0; r < 4; r++)
            Ob[(size_t)(g * 4 + r) * 256 + ct * 16 + l15] =
                (_Float16)(acc[ct][r] * ivr[r]);
    }
    if (g == 0) {
        float2 ml;
        ml.x = M;
        ml.y = Lt;
        ML[sb * 4096 + iw + l15] = ml;
    }
}

// ---------------------------------------------------------------------------
// Kernel 3b: combine splits. O = sum_s w_s O_s, w_s = L_s*2^(M_s-Mmax)/denom.
// grid (512, 4), block 256: 8 rows/block, 32 threads/row x 8 c each.
// ---------------------------------------------------------------------------
__global__ __launch_bounds__(256) void attn_combine(
    const _Float16* __restrict__ Opart, const float2* __restrict__ ML,
    ushort* __restrict__ Rt) {
    const int b = blockIdx.y;
    const int i = blockIdx.x * 8 + (threadIdx.x >> 5);
    const int c0 = (threadIdx.x & 31) * 8;
    float m[4], lv[4];
#pragma unroll
    for (int s = 0; s < 4; s++) {
        float2 ml = ML[(size_t)(s * 4 + b) * 4096 + i];
        m[s] = ml.x;
        lv[s] = ml.y;
    }
    float Mmax = fmaxf(fmaxf(m[0], m[1]), fmaxf(m[2], m[3]));
    float w[4], denom = 0.0f;
#pragma unroll
    for (int s = 0; s < 4; s++) {
        w[s] = lv[s] * exp2f(m[s] - Mmax);
        denom += w[s];
    }
    float inv = 1.0f / denom;
    float o[8] = {0, 0, 0, 0, 0, 0, 0, 0};
#pragma unroll
    for (int s = 0; s < 4; s++) {
        float ws = w[s] * inv;
        f16x8 v = *(const f16x8*)(Opart + ((size_t)(s * 4 + b) * 4096 + i) * 256 + c0);
#pragma unroll
        for (int e = 0; e < 8; e++) o[e] += ws * (float)v[e];
    }
    u16x8 r;
#pragma unroll
    for (int e = 0; e < 8; e++) r[e] = f2bf(o[e]);
    *(u16x8*)(Rt + ((size_t)b * 4096 + i) * 256 + c0) = r;
}

// ---------------------------------------------------------------------------
// Kernel 4: out[o,i] = wo[o,:]·Rt[i,:] + bo[o], fp32 out [C][N].
// grid (256, B), block 256
// ---------------------------------------------------------------------------
__global__ __launch_bounds__(256) void out_proj(
    const ushort* __restrict__ wob, const ushort* __restrict__ Rt,
    const float* __restrict__ bo, float* __restrict__ Out) {
    const int b = blockIdx.y;
    const int m0 = (blockIdx.x & 3) * 64;
    const int n0 = (blockIdx.x >> 2) * 64;
    const int l = threadIdx.x & 63, wv = threadIdx.x >> 6;
    const int g = l >> 4, l15 = l & 15;
    const ushort* Bp = Rt + (size_t)b * 4096 * 256;
    float* Ob = Out + (size_t)b * 256 * 4096;
    const int mrow = m0 + wv * 16 + l15;

    f32x4 acc[4] = {{0, 0, 0, 0}, {0, 0, 0, 0}, {0, 0, 0, 0}, {0, 0, 0, 0}};
#pragma unroll
    for (int kk = 0; kk < 8; kk++) {
        bf16x8 af = *(const bf16x8*)(wob + (size_t)mrow * 256 + kk * 32 + g * 8);
#pragma unroll
        for (int nt = 0; nt < 4; nt++) {
            bf16x8 bfr = *(const bf16x8*)(Bp + (size_t)(n0 + nt * 16 + l15) * 256 + kk * 32 + g * 8);
            acc[nt] = MFMA16(af, bfr, acc[nt]);
        }
    }
#pragma unroll
    for (int nt = 0; nt < 4; nt++) {
#pragma unroll
        for (int r = 0; r < 4; r++) {
            int mr = m0 + wv * 16 + g * 4 + r;
            Ob[(size_t)mr * 4096 + n0 + nt * 16 + l15] = acc[nt][r] + bo[mr];
        }
    }
}

// ---------------------------------------------------------------------------
extern "C" void kernel_launch(void* const* d_in, const int* in_sizes, int n_in,
                              void* d_out, int out_size, void* d_ws, size_t ws_size,
                              hipStream_t stream) {
    const float* Fc = (const float*)d_in[0];
    const float* Fs = (const float*)d_in[1];
    const float* wf = (const float*)d_in[2];
    const float* bf_ = (const float*)d_in[3];
    const float* wg = (const float*)d_in[4];
    const float* bg = (const float*)d_in[5];
    const float* wh = (const float*)d_in[6];
    const float* bh = (const float*)d_in[7];
    const float* wo = (const float*)d_in[8];
    const float* bo = (const float*)d_in[9];
    float* Out = (float*)d_out;

    char* ws = (char*)d_ws;
    const size_t SZ = (size_t)4 * 4096 * 256 * 2;  // 8 MB per [B][4096][256] bf16
    ushort* QHp = (ushort*)(ws + 0 * SZ);
    ushort* QLp = (ushort*)(ws + 1 * SZ);
    ushort* KHp = (ushort*)(ws + 2 * SZ);
    ushort* KLp = (ushort*)(ws + 3 * SZ);
    ushort* Vv  = (ushort*)(ws + 4 * SZ);
    ushort* XcH = (ushort*)(ws + 5 * SZ);
    ushort* XcL = (ushort*)(ws + 6 * SZ);
    ushort* XsH = (ushort*)(ws + 7 * SZ);
    ushort* XsL = (ushort*)(ws + 8 * SZ);
    // Opart aliases XcH..XsL (dead after projections): 4 splits x 8 MB fp16
    _Float16* Opart = (_Float16*)(ws + 5 * SZ);
    char* wsw = ws + 9 * SZ;
    ushort* wfh = (ushort*)(wsw + 0 * 131072);
    ushort* wfl = (ushort*)(wsw + 1 * 131072);
    ushort* wgh = (ushort*)(wsw + 2 * 131072);
    ushort* wgl = (ushort*)(wsw + 3 * 131072);
    ushort* whb = (ushort*)(wsw + 4 * 131072);
    ushort* wob = (ushort*)(wsw + 5 * 131072);
    float2* ML = (float2*)(wsw + 6 * 131072);  // 4*4*4096*8 = 512 KB
    ushort* Rt = QHp;  // alias: Q dead once attn_split completes

    transpose_split<<<dim3(64, 4, 8), 256, 0, stream>>>(Fc, Fs, XcH, XcL, XsH, XsL);
    convert_weights<<<dim3(256), 256, 0, stream>>>(wf, wg, wh, wo, wfh, wfl, wgh, wgl, whb, wob);
    proj_qk<<<dim3(256, 8), 256, 0, stream>>>(XcH, XcL, XsH, XsL, wfh, wfl, wgh, wgl,
                                              bf_, bg, QHp, QLp, KHp, KLp);
    proj_v<<<dim3(256, 4), 256, 0, stream>>>(XsH, whb, bh, Vv);
    attn_split<<<dim3(512), 512, 0, stream>>>(QHp, QLp, KHp, KLp, Vv, Opart, ML);
    attn_combine<<<dim3(512, 4), 256, 0, stream>>>(Opart, ML, Rt);
    out_proj<<<dim3(256, 4), 256, 0, stream>>>(wob, Rt, bo, Out);
}

// Round 5
// 352.852 us; speedup vs baseline: 3.1874x; 1.1583x over previous
//
#include <hip/hip_runtime.h>
#include <hip/hip_bf16.h>

typedef __attribute__((ext_vector_type(8))) short bf16x8;
typedef __attribute__((ext_vector_type(4))) float f32x4;
typedef __attribute__((ext_vector_type(8))) _Float16 f16x8;
typedef __attribute__((ext_vector_type(8))) unsigned short u16x8;
typedef __attribute__((ext_vector_type(4))) unsigned short u16x4;
typedef unsigned int uint32;
typedef unsigned short ushort;

#define MFMA16(a, b, c) __builtin_amdgcn_mfma_f32_16x16x32_bf16((a), (b), (c), 0, 0, 0)
#define MFMA16F(a, b, c) __builtin_amdgcn_mfma_f32_16x16x32_f16((a), (b), (c), 0, 0, 0)

__device__ __forceinline__ ushort f2bf(float f) {
    __hip_bfloat16 h = __float2bfloat16(f);
    return __builtin_bit_cast(ushort, h);
}
__device__ __forceinline__ float bf2f(ushort u) {
    uint32 v = ((uint32)u) << 16;
    return __builtin_bit_cast(float, v);
}
// async global->LDS, 16B per lane; lds dest = uniform base + lane*16
__device__ __forceinline__ void gld16(const ushort* g, ushort* l) {
    __builtin_amdgcn_global_load_lds(
        (const __attribute__((address_space(1))) unsigned int*)g,
        (__attribute__((address_space(3))) unsigned int*)l, 16, 0, 0);
}

// ---------------------------------------------------------------------------
// Kernel 1a: transpose fp32 [C=256][N=4096] -> bf16 hi/lo [N][C]
// grid (64, 4, 8), block 256. float4 loads, u16x4 stores.
// ---------------------------------------------------------------------------
__global__ __launch_bounds__(256) void transpose_split(
    const float* __restrict__ Fc, const float* __restrict__ Fs,
    ushort* __restrict__ XcH, ushort* __restrict__ XcL,
    ushort* __restrict__ XsH, ushort* __restrict__ XsL) {
    __shared__ float lds[64][65];  // [i-local][c-local]
    const int z = blockIdx.z;
    const int b = z & 3;
    const float* src = (z < 4) ? Fc : Fs;
    ushort* dh = (z < 4) ? XcH : XsH;
    ushort* dl = (z < 4) ? XcL : XsL;
    src += (size_t)b * 256 * 4096;
    dh += (size_t)b * 4096 * 256;
    dl += (size_t)b * 4096 * 256;
    const int i0 = blockIdx.x * 64;
    const int c0 = blockIdx.y * 64;
    const int t = threadIdx.x;
    const int rq = t >> 4;        // 0..15
    const int q4 = (t & 15) * 4;  // 0..60
#pragma unroll
    for (int p = 0; p < 4; p++) {
        int r = rq + p * 16;  // c-local
        float4 v = *(const float4*)(src + (size_t)(c0 + r) * 4096 + i0 + q4);
        lds[q4 + 0][r] = v.x;
        lds[q4 + 1][r] = v.y;
        lds[q4 + 2][r] = v.z;
        lds[q4 + 3][r] = v.w;
    }
    __syncthreads();
#pragma unroll
    for (int p = 0; p < 4; p++) {
        int i = rq + p * 16;  // i-local
        u16x4 hv, lv;
#pragma unroll
        for (int e = 0; e < 4; e++) {
            float f = lds[i][q4 + e];
            ushort hb = f2bf(f);
            hv[e] = hb;
            lv[e] = f2bf(f - bf2f(hb));
        }
        *(u16x4*)(dh + (size_t)(i0 + i) * 256 + c0 + q4) = hv;
        *(u16x4*)(dl + (size_t)(i0 + i) * 256 + c0 + q4) = lv;
    }
}

// ---------------------------------------------------------------------------
// Kernel 1b: weights fp32 -> bf16; w_f scaled by log2e, w_f/w_g split hi/lo.
// grid 256, block 256
// ---------------------------------------------------------------------------
__global__ __launch_bounds__(256) void convert_weights(
    const float* __restrict__ wf, const float* __restrict__ wg,
    const float* __restrict__ wh, const float* __restrict__ wo,
    ushort* __restrict__ wfh, ushort* __restrict__ wfl,
    ushort* __restrict__ wgh, ushort* __restrict__ wgl,
    ushort* __restrict__ whb, ushort* __restrict__ wob) {
    const int t = blockIdx.x * 256 + threadIdx.x;  // 0..65535
    const float L2E = 1.4426950408889634f;
    float sf = wf[t] * L2E;
    ushort hf = f2bf(sf);
    wfh[t] = hf;
    wfl[t] = f2bf(sf - bf2f(hf));
    float sg = wg[t];
    ushort hg = f2bf(sg);
    wgh[t] = hg;
    wgl[t] = f2bf(sg - bf2f(hg));
    whb[t] = f2bf(wh[t]);
    wob[t] = f2bf(wo[t]);
}

// ---------------------------------------------------------------------------
// Kernel 2a: Q/K projection, split-precision inputs, fp16 outputs.
// grid (256, 8), block 256 (4 waves, tile 64x64, wave = 16m x 64n)
// ---------------------------------------------------------------------------
__global__ __launch_bounds__(256) void proj_qk(
    const ushort* __restrict__ XcH, const ushort* __restrict__ XcL,
    const ushort* __restrict__ XsH, const ushort* __restrict__ XsL,
    const ushort* __restrict__ wfh, const ushort* __restrict__ wfl,
    const ushort* __restrict__ wgh, const ushort* __restrict__ wgl,
    const float* __restrict__ bf_, const float* __restrict__ bg_,
    _Float16* __restrict__ QF, _Float16* __restrict__ KF) {
    const int y = blockIdx.y;
    const int isK = y >> 2;
    const int b = y & 3;
    const size_t bNC = (size_t)b * 4096 * 256;
    const ushort* Ah = (isK ? XsH : XcH) + bNC;
    const ushort* Al = (isK ? XsL : XcL) + bNC;
    const ushort* Bh = isK ? wgh : wfh;
    const ushort* Bl = isK ? wgl : wfl;
    const float* bias = isK ? bg_ : bf_;
    const float bscale = isK ? 1.0f : 1.4426950408889634f;
    _Float16* Co = (isK ? KF : QF) + bNC;
    const int m0 = (blockIdx.x & 63) * 64, n0 = (blockIdx.x >> 6) * 64;
    const int l = threadIdx.x & 63, wv = threadIdx.x >> 6;
    const int g = l >> 4, l15 = l & 15;
    const int mrow = m0 + wv * 16 + l15;

    f32x4 acc[4] = {{0, 0, 0, 0}, {0, 0, 0, 0}, {0, 0, 0, 0}, {0, 0, 0, 0}};
#pragma unroll
    for (int kk = 0; kk < 8; kk++) {
        bf16x8 ah = *(const bf16x8*)(Ah + (size_t)mrow * 256 + kk * 32 + g * 8);
        bf16x8 al = *(const bf16x8*)(Al + (size_t)mrow * 256 + kk * 32 + g * 8);
#pragma unroll
        for (int nt = 0; nt < 4; nt++) {
            const size_t boff = (size_t)(n0 + nt * 16 + l15) * 256 + kk * 32 + g * 8;
            bf16x8 bh = *(const bf16x8*)(Bh + boff);
            bf16x8 bl = *(const bf16x8*)(Bl + boff);
            acc[nt] = MFMA16(ah, bh, acc[nt]);
            acc[nt] = MFMA16(ah, bl, acc[nt]);
            acc[nt] = MFMA16(al, bh, acc[nt]);
        }
    }
#pragma unroll
    for (int nt = 0; nt < 4; nt++) {
        float bn = bias[n0 + nt * 16 + l15] * bscale;
#pragma unroll
        for (int r = 0; r < 4; r++) {
            int mr = m0 + wv * 16 + g * 4 + r;
            Co[(size_t)mr * 256 + n0 + nt * 16 + l15] = (_Float16)(acc[nt][r] + bn);
        }
    }
}

// ---------------------------------------------------------------------------
// Kernel 2b: V projection. V[o,j] = wh[o,:]·Xs[j,:] + bh[o], ldc=4096, bf16.
// grid (256, 4), block 256
// ---------------------------------------------------------------------------
__global__ __launch_bounds__(256) void proj_v(
    const ushort* __restrict__ XsH, const ushort* __restrict__ whb,
    const float* __restrict__ bh_, ushort* __restrict__ Vv) {
    const int b = blockIdx.y;
    const size_t bNC = (size_t)b * 4096 * 256;
    const ushort* A = whb;
    const ushort* Bp = XsH + bNC;
    ushort* Cp = Vv + bNC;
    const int m0 = (blockIdx.x & 3) * 64, n0 = (blockIdx.x >> 2) * 64;
    const int l = threadIdx.x & 63, wv = threadIdx.x >> 6;
    const int g = l >> 4, l15 = l & 15;
    const int mrow = m0 + wv * 16 + l15;

    f32x4 acc[4] = {{0, 0, 0, 0}, {0, 0, 0, 0}, {0, 0, 0, 0}, {0, 0, 0, 0}};
#pragma unroll
    for (int kk = 0; kk < 8; kk++) {
        bf16x8 af = *(const bf16x8*)(A + (size_t)mrow * 256 + kk * 32 + g * 8);
#pragma unroll
        for (int nt = 0; nt < 4; nt++) {
            bf16x8 bfr = *(const bf16x8*)(Bp + (size_t)(n0 + nt * 16 + l15) * 256 + kk * 32 + g * 8);
            acc[nt] = MFMA16(af, bfr, acc[nt]);
        }
    }
#pragma unroll
    for (int nt = 0; nt < 4; nt++) {
#pragma unroll
        for (int r = 0; r < 4; r++) {
            int mr = m0 + wv * 16 + g * 4 + r;
            Cp[(size_t)mr * 4096 + n0 + nt * 16 + l15] = f2bf(acc[nt][r] + bh_[mr]);
        }
    }
}

// ---------------------------------------------------------------------------
// Kernel 3: flash attention. KV-split S=2, fp16 QK, double-buffered LDS,
// defer-max softmax. grid 256 (8 (b,s)-groups, 1/XCD, x 32 q-tiles),
// block 512 = 8 waves x 16 q. One barrier per 32-key tile.
// ---------------------------------------------------------------------------
__global__ __launch_bounds__(512, 2) void attn_split(
    const _Float16* __restrict__ QF, const _Float16* __restrict__ KF,
    const ushort* __restrict__ Vv, _Float16* __restrict__ Opart,
    float2* __restrict__ ML) {
    __shared__ __align__(16) _Float16 Kf[2][32 * 256];  // 16KB x2, chunk^=row swizzle
    __shared__ __align__(16) ushort Vt[2][256 * 40];    // 20KB x2, pitch 40 (pad)

    const int h = blockIdx.x;  // 0..255
    const int grp = h & 7;     // one (b,s) group per XCD
    const int itile = h >> 3;  // 0..31
    const int b = grp >> 1;
    const int s = grp & 1;

    const int tid = threadIdx.x;
    const int l = tid & 63, wv = tid >> 6;
    const int g = l >> 4, l15 = l & 15;
    const int iw = itile * 128 + wv * 16;
    const _Float16* Qb = QF + ((size_t)b * 4096 + iw) * 256;
    const _Float16* Kb = KF + (size_t)b * 4096 * 256;
    const ushort* Vb = Vv + (size_t)b * 4096 * 256;  // [256][4096]

    f16x8 qf[8];
#pragma unroll
    for (int kk = 0; kk < 8; kk++)
        qf[kk] = *(const f16x8*)(Qb + (size_t)l15 * 256 + kk * 32 + g * 8);

    // V staging assignment: thread -> (channel, 16-key half)
    const int vch = tid >> 1;
    const int vko = (tid & 1) * 16;
    const ushort* Vsrc = Vb + (size_t)vch * 4096;

    f32x4 acc[16];
#pragma unroll
    for (int ct = 0; ct < 16; ct++) acc[ct] = (f32x4){0, 0, 0, 0};
    float M = -INFINITY, Lsum = 0.0f;

    const int jbeg = s * 2048, jend = jbeg + 2048;

    auto stageK = [&](int buf, int jj) {
        const _Float16* ks = Kb + (size_t)jj * 256;
#pragma unroll
        for (int q = 0; q < 2; q++) {
            int issue = wv * 2 + q;              // 0..15
            int row = issue * 2 + (l >> 5);      // 0..31
            int scol = ((l & 31) ^ row) * 8;     // pre-swizzled source chunk
            gld16((const ushort*)(ks + (size_t)row * 256 + scol),
                  (ushort*)&Kf[buf][issue * 512]);
        }
    };

    // prologue: stage tile 0 into buffer 0
    stageK(0, jbeg);
    {
        u16x8 va = *(const u16x8*)(Vsrc + jbeg + vko);
        u16x8 vb2 = *(const u16x8*)(Vsrc + jbeg + vko + 8);
        asm volatile("s_waitcnt vmcnt(0)" ::: "memory");
        *(u16x8*)&Vt[0][vch * 40 + vko] = va;
        *(u16x8*)&Vt[0][vch * 40 + vko + 8] = vb2;
    }
    __syncthreads();

    int cur = 0;
    for (int j0 = jbeg; j0 < jend; j0 += 32) {
        const bool pre = (j0 + 32) < jend;
        u16x8 va, vb2;
        if (pre) {
            stageK(cur ^ 1, j0 + 32);
            va = *(const u16x8*)(Vsrc + (j0 + 32) + vko);
            vb2 = *(const u16x8*)(Vsrc + (j0 + 32) + vko + 8);
        }
        // ---- QK^T (fp16, 4 independent chains) ----
        f32x4 s0e = {0, 0, 0, 0}, s0o = {0, 0, 0, 0};
        f32x4 s1e = {0, 0, 0, 0}, s1o = {0, 0, 0, 0};
        const int r1 = l15 + 16;
#pragma unroll
        for (int kk = 0; kk < 8; kk += 2) {
            {
                int cs = kk * 4 + g;
                f16x8 k0 = *(const f16x8*)&Kf[cur][l15 * 256 + ((cs ^ l15) & 31) * 8];
                f16x8 k1 = *(const f16x8*)&Kf[cur][r1 * 256 + ((cs ^ r1) & 31) * 8];
                s0e = MFMA16F(k0, qf[kk], s0e);
                s1e = MFMA16F(k1, qf[kk], s1e);
            }
            {
                int cs = (kk + 1) * 4 + g;
                f16x8 k0 = *(const f16x8*)&Kf[cur][l15 * 256 + ((cs ^ l15) & 31) * 8];
                f16x8 k1 = *(const f16x8*)&Kf[cur][r1 * 256 + ((cs ^ r1) & 31) * 8];
                s0o = MFMA16F(k0, qf[kk + 1], s0o);
                s1o = MFMA16F(k1, qf[kk + 1], s1o);
            }
        }
        f32x4 s0 = s0e + s0o;
        f32x4 s1 = s1e + s1o;
        // lane holds S^T: query i = iw+l15; j = j0 + 16*t + g*4 + r
        float tm = fmaxf(fmaxf(fmaxf(s0[0], s0[1]), fmaxf(s0[2], s0[3])),
                         fmaxf(fmaxf(s1[0], s1[1]), fmaxf(s1[2], s1[3])));
        tm = fmaxf(tm, __shfl_xor(tm, 16));
        tm = fmaxf(tm, __shfl_xor(tm, 32));
        // defer-max: only rescale when some query's max grew by > 8 (log2)
        if (__any(tm - M > 8.0f)) {
            float newM = fmaxf(M, tm);
            float alpha = exp2f(M - newM);  // 0 on first tile
            Lsum *= alpha;
            float ar[4];
#pragma unroll
            for (int r = 0; r < 4; r++) ar[r] = __shfl(alpha, g * 4 + r);
#pragma unroll
            for (int ct = 0; ct < 16; ct++) {
#pragma unroll
                for (int r = 0; r < 4; r++) acc[ct][r] *= ar[r];
            }
            M = newM;
        }
        float p[8];
#pragma unroll
        for (int r = 0; r < 4; r++) {
            p[r] = exp2f(s0[r] - M);      // bounded by 2^8
            p[4 + r] = exp2f(s1[r] - M);
        }
        Lsum += p[0] + p[1] + p[2] + p[3] + p[4] + p[5] + p[6] + p[7];

        uint32 pk[4];
        pk[0] = (uint32)f2bf(p[0]) | ((uint32)f2bf(p[1]) << 16);  // s0, j+{0,1}
        pk[1] = (uint32)f2bf(p[2]) | ((uint32)f2bf(p[3]) << 16);  // s0, j+{2,3}
        pk[2] = (uint32)f2bf(p[4]) | ((uint32)f2bf(p[5]) << 16);  // s1, j+{0,1}
        pk[3] = (uint32)f2bf(p[6]) | ((uint32)f2bf(p[7]) << 16);  // s1, j+{2,3}
        // gather PV A-fragment: lane (g,l15) needs P[i=l15][j = j0 + g*8 + 0..7]
        const int ts = g >> 1;
        const int s1l = l15 + ((g & 1) << 5);
        uint32 w0a = __shfl(pk[0], s1l), w0b = __shfl(pk[2], s1l);
        uint32 w1a = __shfl(pk[1], s1l), w1b = __shfl(pk[3], s1l);
        uint32 w2a = __shfl(pk[0], s1l + 16), w2b = __shfl(pk[2], s1l + 16);
        uint32 w3a = __shfl(pk[1], s1l + 16), w3b = __shfl(pk[3], s1l + 16);
        union { uint32 u[4]; bf16x8 v; } pun;
        pun.u[0] = ts ? w0b : w0a;
        pun.u[1] = ts ? w1b : w1a;
        pun.u[2] = ts ? w2b : w2a;
        pun.u[3] = ts ? w3b : w3a;
        bf16x8 pf = pun.v;

        // ---- PV from padded LDS V tile (conflict-free) ----
#pragma unroll
        for (int ct = 0; ct < 16; ct++) {
            bf16x8 vf = *(const bf16x8*)&Vt[cur][(ct * 16 + l15) * 40 + g * 8];
            acc[ct] = MFMA16(pf, vf, acc[ct]);
        }
        if (pre) {
            asm volatile("s_waitcnt vmcnt(0)" ::: "memory");
            *(u16x8*)&Vt[cur ^ 1][vch * 40 + vko] = va;
            *(u16x8*)&Vt[cur ^ 1][vch * 40 + vko + 8] = vb2;
        }
        __syncthreads();
        cur ^= 1;
    }
    float Lt = Lsum + __shfl_xor(Lsum, 16);
    Lt += __shfl_xor(Lt, 32);
    float inv = 1.0f / Lt;
    float ivr[4];
#pragma unroll
    for (int r = 0; r < 4; r++) ivr[r] = __shfl(inv, g * 4 + r);
    const size_t sb = (size_t)(s * 4 + b);
    _Float16* Ob = Opart + (sb * 4096 + iw) * 256;
#pragma unroll
    for (int ct = 0; ct < 16; ct++) {
#pragma unroll
        for (int r = 0; r < 4; r++)
            Ob[(size_t)(g * 4 + r) * 256 + ct * 16 + l15] =
                (_Float16)(acc[ct][r] * ivr[r]);
    }
    if (g == 0) {
        float2 ml;
        ml.x = M;
        ml.y = Lt;
        ML[sb * 4096 + iw + l15] = ml;
    }
}

// ---------------------------------------------------------------------------
// Kernel 3b: combine 2 splits. grid (512, 4), block 256.
// ---------------------------------------------------------------------------
__global__ __launch_bounds__(256) void attn_combine(
    const _Float16* __restrict__ Opart, const float2* __restrict__ ML,
    ushort* __restrict__ Rt) {
    const int b = blockIdx.y;
    const int i = blockIdx.x * 8 + (threadIdx.x >> 5);
    const int c0 = (threadIdx.x & 31) * 8;
    float2 ml0 = ML[(size_t)(0 * 4 + b) * 4096 + i];
    float2 ml1 = ML[(size_t)(1 * 4 + b) * 4096 + i];
    float Mmax = fmaxf(ml0.x, ml1.x);
    float w0 = ml0.y * exp2f(ml0.x - Mmax);
    float w1 = ml1.y * exp2f(ml1.x - Mmax);
    float inv = 1.0f / (w0 + w1);
    w0 *= inv;
    w1 *= inv;
    f16x8 v0 = *(const f16x8*)(Opart + ((size_t)(0 * 4 + b) * 4096 + i) * 256 + c0);
    f16x8 v1 = *(const f16x8*)(Opart + ((size_t)(1 * 4 + b) * 4096 + i) * 256 + c0);
    u16x8 r;
#pragma unroll
    for (int e = 0; e < 8; e++) r[e] = f2bf(w0 * (float)v0[e] + w1 * (float)v1[e]);
    *(u16x8*)(Rt + ((size_t)b * 4096 + i) * 256 + c0) = r;
}

// ---------------------------------------------------------------------------
// Kernel 4: out[o,i] = wo[o,:]·Rt[i,:] + bo[o], fp32 out [C][N].
// grid (256, B), block 256
// ---------------------------------------------------------------------------
__global__ __launch_bounds__(256) void out_proj(
    const ushort* __restrict__ wob, const ushort* __restrict__ Rt,
    const float* __restrict__ bo, float* __restrict__ Out) {
    const int b = blockIdx.y;
    const int m0 = (blockIdx.x & 3) * 64;
    const int n0 = (blockIdx.x >> 2) * 64;
    const int l = threadIdx.x & 63, wv = threadIdx.x >> 6;
    const int g = l >> 4, l15 = l & 15;
    const ushort* Bp = Rt + (size_t)b * 4096 * 256;
    float* Ob = Out + (size_t)b * 256 * 4096;
    const int mrow = m0 + wv * 16 + l15;

    f32x4 acc[4] = {{0, 0, 0, 0}, {0, 0, 0, 0}, {0, 0, 0, 0}, {0, 0, 0, 0}};
#pragma unroll
    for (int kk = 0; kk < 8; kk++) {
        bf16x8 af = *(const bf16x8*)(wob + (size_t)mrow * 256 + kk * 32 + g * 8);
#pragma unroll
        for (int nt = 0; nt < 4; nt++) {
            bf16x8 bfr = *(const bf16x8*)(Bp + (size_t)(n0 + nt * 16 + l15) * 256 + kk * 32 + g * 8);
            acc[nt] = MFMA16(af, bfr, acc[nt]);
        }
    }
#pragma unroll
    for (int nt = 0; nt < 4; nt++) {
#pragma unroll
        for (int r = 0; r < 4; r++) {
            int mr = m0 + wv * 16 + g * 4 + r;
            Ob[(size_t)mr * 4096 + n0 + nt * 16 + l15] = acc[nt][r] + bo[mr];
        }
    }
}

// ---------------------------------------------------------------------------
extern "C" void kernel_launch(void* const* d_in, const int* in_sizes, int n_in,
                              void* d_out, int out_size, void* d_ws, size_t ws_size,
                              hipStream_t stream) {
    const float* Fc = (const float*)d_in[0];
    const float* Fs = (const float*)d_in[1];
    const float* wf = (const float*)d_in[2];
    const float* bf_ = (const float*)d_in[3];
    const float* wg = (const float*)d_in[4];
    const float* bg = (const float*)d_in[5];
    const float* wh = (const float*)d_in[6];
    const float* bh = (const float*)d_in[7];
    const float* wo = (const float*)d_in[8];
    const float* bo = (const float*)d_in[9];
    float* Out = (float*)d_out;

    char* ws = (char*)d_ws;
    const size_t SZ = (size_t)4 * 4096 * 256 * 2;  // 8 MB per [B][4096][256] 16-bit
    _Float16* QFp = (_Float16*)(ws + 0 * SZ);
    _Float16* KFp = (_Float16*)(ws + 1 * SZ);
    ushort* Vv  = (ushort*)(ws + 2 * SZ);
    ushort* XcH = (ushort*)(ws + 3 * SZ);
    ushort* XcL = (ushort*)(ws + 4 * SZ);
    ushort* XsH = (ushort*)(ws + 5 * SZ);
    ushort* XsL = (ushort*)(ws + 6 * SZ);
    // Opart aliases XcH..XsL (dead after projections): [8][4096][256] fp16 = 16MB
    _Float16* Opart = (_Float16*)(ws + 3 * SZ);
    char* wsw = ws + 7 * SZ;
    ushort* wfh = (ushort*)(wsw + 0 * 131072);
    ushort* wfl = (ushort*)(wsw + 1 * 131072);
    ushort* wgh = (ushort*)(wsw + 2 * 131072);
    ushort* wgl = (ushort*)(wsw + 3 * 131072);
    ushort* whb = (ushort*)(wsw + 4 * 131072);
    ushort* wob = (ushort*)(wsw + 5 * 131072);
    float2* ML = (float2*)(wsw + 6 * 131072);  // 8*4096*8 = 256 KB
    ushort* Rt = (ushort*)QFp;  // alias: Q dead once attn_split completes

    transpose_split<<<dim3(64, 4, 8), 256, 0, stream>>>(Fc, Fs, XcH, XcL, XsH, XsL);
    convert_weights<<<dim3(256), 256, 0, stream>>>(wf, wg, wh, wo, wfh, wfl, wgh, wgl, whb, wob);
    proj_qk<<<dim3(256, 8), 256, 0, stream>>>(XcH, XcL, XsH, XsL, wfh, wfl, wgh, wgl,
                                              bf_, bg, QFp, KFp);
    proj_v<<<dim3(256, 4), 256, 0, stream>>>(XsH, whb, bh, Vv);
    attn_split<<<dim3(256), 512, 0, stream>>>(QFp, KFp, Vv, Opart, ML);
    attn_combine<<<dim3(512, 4), 256, 0, stream>>>(Opart, ML, Rt);
    out_proj<<<dim3(256, 4), 256, 0, stream>>>(wob, Rt, bo, Out);
}

// Round 6
// 332.859 us; speedup vs baseline: 3.3789x; 1.0601x over previous
//
#include <hip/hip_runtime.h>
#include <hip/hip_bf16.h>

typedef __attribute__((ext_vector_type(4))) float f32x4;
typedef __attribute__((ext_vector_type(16))) float f32x16;
typedef __attribute__((ext_vector_type(8))) _Float16 f16x8;
typedef __attribute__((ext_vector_type(4))) _Float16 f16x4;
typedef unsigned int uint32;
typedef unsigned short ushort;

#define MFMA16F(a, b, c) __builtin_amdgcn_mfma_f32_16x16x32_f16((a), (b), (c), 0, 0, 0)
#define MFMA32F(a, b, c) __builtin_amdgcn_mfma_f32_32x32x16_f16((a), (b), (c), 0, 0, 0)

__device__ __forceinline__ uint32 pkf16(float a, float b) {
    ushort ua = __builtin_bit_cast(ushort, (_Float16)a);
    ushort ub = __builtin_bit_cast(ushort, (_Float16)b);
    return (uint32)ua | ((uint32)ub << 16);
}
// async global->LDS, 16B per lane; lds dest = uniform base + lane*16
__device__ __forceinline__ void gld16(const _Float16* g, _Float16* l) {
    __builtin_amdgcn_global_load_lds(
        (const __attribute__((address_space(1))) unsigned int*)g,
        (__attribute__((address_space(3))) unsigned int*)l, 16, 0, 0);
}

// ---------------------------------------------------------------------------
// Kernel 1a: transpose fp32 [C=256][N=4096] -> f16 [N][C] for F_c and F_s.
// grid (64, 4, 8), block 256
// ---------------------------------------------------------------------------
__global__ __launch_bounds__(256) void transpose_f16(
    const float* __restrict__ Fc, const float* __restrict__ Fs,
    _Float16* __restrict__ Xc, _Float16* __restrict__ Xs) {
    __shared__ float lds[64][65];  // [i-local][c-local]
    const int z = blockIdx.z;
    const int b = z & 3;
    const float* src = (z < 4) ? Fc : Fs;
    _Float16* dst = (z < 4) ? Xc : Xs;
    src += (size_t)b * 256 * 4096;
    dst += (size_t)b * 4096 * 256;
    const int i0 = blockIdx.x * 64;
    const int c0 = blockIdx.y * 64;
    const int t = threadIdx.x;
    const int rq = t >> 4;        // 0..15
    const int q4 = (t & 15) * 4;  // 0..60
#pragma unroll
    for (int p = 0; p < 4; p++) {
        int r = rq + p * 16;  // c-local
        float4 v = *(const float4*)(src + (size_t)(c0 + r) * 4096 + i0 + q4);
        lds[q4 + 0][r] = v.x;
        lds[q4 + 1][r] = v.y;
        lds[q4 + 2][r] = v.z;
        lds[q4 + 3][r] = v.w;
    }
    __syncthreads();
#pragma unroll
    for (int p = 0; p < 4; p++) {
        int i = rq + p * 16;  // i-local
        f16x4 hv;
#pragma unroll
        for (int e = 0; e < 4; e++) hv[e] = (_Float16)lds[i][q4 + e];
        *(f16x4*)(dst + (size_t)(i0 + i) * 256 + c0 + q4) = hv;
    }
}

// ---------------------------------------------------------------------------
// Kernel 1b: weights fp32 -> f16; w_f scaled by log2e; w_f/w_g split hi/lo.
// grid 256, block 256
// ---------------------------------------------------------------------------
__global__ __launch_bounds__(256) void convert_weights(
    const float* __restrict__ wf, const float* __restrict__ wg,
    const float* __restrict__ wh, const float* __restrict__ wo,
    _Float16* __restrict__ wfh, _Float16* __restrict__ wfl,
    _Float16* __restrict__ wgh, _Float16* __restrict__ wgl,
    _Float16* __restrict__ whb, _Float16* __restrict__ wob) {
    const int t = blockIdx.x * 256 + threadIdx.x;  // 0..65535
    const float L2E = 1.4426950408889634f;
    float sf = wf[t] * L2E;
    _Float16 hf = (_Float16)sf;
    wfh[t] = hf;
    wfl[t] = (_Float16)(sf - (float)hf);
    float sg = wg[t];
    _Float16 hg = (_Float16)sg;
    wgh[t] = hg;
    wgl[t] = (_Float16)(sg - (float)hg);
    whb[t] = (_Float16)wh[t];
    wob[t] = (_Float16)wo[t];
}

// ---------------------------------------------------------------------------
// Kernel 2a: Q/K projection, f16 X single + f16 hi/lo weights (2-term).
// grid (256, 8), block 256 (4 waves, tile 64x64, wave = 16m x 64n)
// ---------------------------------------------------------------------------
__global__ __launch_bounds__(256) void proj_qk(
    const _Float16* __restrict__ Xc, const _Float16* __restrict__ Xs,
    const _Float16* __restrict__ wfh, const _Float16* __restrict__ wfl,
    const _Float16* __restrict__ wgh, const _Float16* __restrict__ wgl,
    const float* __restrict__ bf_, const float* __restrict__ bg_,
    _Float16* __restrict__ QF, _Float16* __restrict__ KF) {
    const int y = blockIdx.y;
    const int isK = y >> 2;
    const int b = y & 3;
    const size_t bNC = (size_t)b * 4096 * 256;
    const _Float16* A = (isK ? Xs : Xc) + bNC;
    const _Float16* Bh = isK ? wgh : wfh;
    const _Float16* Bl = isK ? wgl : wfl;
    const float* bias = isK ? bg_ : bf_;
    const float bscale = isK ? 1.0f : 1.4426950408889634f;
    _Float16* Co = (isK ? KF : QF) + bNC;
    const int m0 = (blockIdx.x & 63) * 64, n0 = (blockIdx.x >> 6) * 64;
    const int l = threadIdx.x & 63, wv = threadIdx.x >> 6;
    const int g = l >> 4, l15 = l & 15;
    const int mrow = m0 + wv * 16 + l15;

    f32x4 acc[4] = {{0, 0, 0, 0}, {0, 0, 0, 0}, {0, 0, 0, 0}, {0, 0, 0, 0}};
#pragma unroll
    for (int kk = 0; kk < 8; kk++) {
        f16x8 a = *(const f16x8*)(A + (size_t)mrow * 256 + kk * 32 + g * 8);
#pragma unroll
        for (int nt = 0; nt < 4; nt++) {
            const size_t boff = (size_t)(n0 + nt * 16 + l15) * 256 + kk * 32 + g * 8;
            f16x8 bh = *(const f16x8*)(Bh + boff);
            f16x8 bl = *(const f16x8*)(Bl + boff);
            acc[nt] = MFMA16F(a, bh, acc[nt]);
            acc[nt] = MFMA16F(a, bl, acc[nt]);
        }
    }
#pragma unroll
    for (int nt = 0; nt < 4; nt++) {
        float bn = bias[n0 + nt * 16 + l15] * bscale;
#pragma unroll
        for (int r = 0; r < 4; r++) {
            int mr = m0 + wv * 16 + g * 4 + r;
            Co[(size_t)mr * 256 + n0 + nt * 16 + l15] = (_Float16)(acc[nt][r] + bn);
        }
    }
}

// ---------------------------------------------------------------------------
// Kernel 2b: V projection, f16. V[o,j] = wh[o,:]·Xs[j,:] + bh[o], ldc=4096.
// grid (256, 4), block 256
// ---------------------------------------------------------------------------
__global__ __launch_bounds__(256) void proj_v(
    const _Float16* __restrict__ Xs, const _Float16* __restrict__ whb,
    const float* __restrict__ bh_, _Float16* __restrict__ VF) {
    const int b = blockIdx.y;
    const size_t bNC = (size_t)b * 4096 * 256;
    const _Float16* Bp = Xs + bNC;
    _Float16* Cp = VF + bNC;
    const int m0 = (blockIdx.x & 3) * 64, n0 = (blockIdx.x >> 2) * 64;
    const int l = threadIdx.x & 63, wv = threadIdx.x >> 6;
    const int g = l >> 4, l15 = l & 15;
    const int mrow = m0 + wv * 16 + l15;

    f32x4 acc[4] = {{0, 0, 0, 0}, {0, 0, 0, 0}, {0, 0, 0, 0}, {0, 0, 0, 0}};
#pragma unroll
    for (int kk = 0; kk < 8; kk++) {
        f16x8 a = *(const f16x8*)(whb + (size_t)mrow * 256 + kk * 32 + g * 8);
#pragma unroll
        for (int nt = 0; nt < 4; nt++) {
            f16x8 bfr = *(const f16x8*)(Bp + (size_t)(n0 + nt * 16 + l15) * 256 + kk * 32 + g * 8);
            acc[nt] = MFMA16F(a, bfr, acc[nt]);
        }
    }
#pragma unroll
    for (int nt = 0; nt < 4; nt++) {
#pragma unroll
        for (int r = 0; r < 4; r++) {
            int mr = m0 + wv * 16 + g * 4 + r;
            Cp[(size_t)mr * 4096 + n0 + nt * 16 + l15] = (_Float16)(acc[nt][r] + bh_[mr]);
        }
    }
}

// ---------------------------------------------------------------------------
// Kernel 3: flash attention, 32x32 MFMA, 32 queries/wave, KV-split S=4.
// grid 256 (16 (b,s) groups, 2/XCD, x 16 q-tiles of 256), block 512.
// Swapped QK^T: S^T[j][i] = mfma32(K-frag, Q-frag); lane (i=l&31, hi=l>>5)
// holds 16 scores j=(r&3)+8*(r>>2)+4*hi. P -> PV A-frag via permlane32_swap.
// Double-buffered LDS K (swizzled, gld_lds) + V (reg-staged, pitch 40).
// ---------------------------------------------------------------------------
__global__ __launch_bounds__(512, 2) void attn_split(
    const _Float16* __restrict__ QF, const _Float16* __restrict__ KF,
    const _Float16* __restrict__ VF, _Float16* __restrict__ Opart,
    float2* __restrict__ ML) {
    __shared__ __align__(16) _Float16 Klds[2][32 * 256];  // 16KB x2
    __shared__ __align__(16) _Float16 Vt[2][256 * 40];    // 20KB x2

    const int h = blockIdx.x;
    const int grp = (h & 7) + 8 * ((h >> 3) & 1);  // 0..15, 2 groups per XCD
    const int itile = h >> 4;                      // 0..15
    const int b = grp & 3, s = grp >> 2;

    const int tid = threadIdx.x;
    const int l = tid & 63, wv = tid >> 6;
    const int i31 = l & 31, hi = l >> 5;
    const int iwq = itile * 256 + wv * 32;
    const _Float16* Qb = QF + ((size_t)b * 4096 + iwq) * 256;
    const _Float16* Kb = KF + (size_t)b * 4096 * 256;
    const _Float16* Vb = VF + (size_t)b * 4096 * 256;  // [256][4096]

    // Q B-frags: lane (i31,hi) holds Q[i31][16t + 8hi .. +7], t=0..15
    f16x8 qf[16];
#pragma unroll
    for (int t = 0; t < 16; t++)
        qf[t] = *(const f16x8*)(Qb + (size_t)i31 * 256 + t * 16 + hi * 8);

    f32x16 acc[8];
#pragma unroll
    for (int ct = 0; ct < 8; ct++)
#pragma unroll
        for (int r = 0; r < 16; r++) acc[ct][r] = 0.0f;
    float M = -INFINITY, Lsum = 0.0f;

    const int vch = tid >> 1, vko = (tid & 1) * 16;
    const _Float16* Vsrc = Vb + (size_t)vch * 4096;

    const int jbeg = s * 1024, jend = jbeg + 1024;

    auto stageK = [&](int buf, int jj) {
        const _Float16* ks = Kb + (size_t)jj * 256;
#pragma unroll
        for (int q = 0; q < 2; q++) {
            int issue = wv * 2 + q;          // 0..15, 1KB each
            int row = issue * 2 + (l >> 5);  // 0..31
            int scol = ((l & 31) ^ (row & 7)) * 8;  // pre-swizzled source
            gld16(ks + (size_t)row * 256 + scol, &Klds[buf][issue * 512]);
        }
    };

    // prologue
    stageK(0, jbeg);
    {
        f16x8 va = *(const f16x8*)(Vsrc + jbeg + vko);
        f16x8 vb2 = *(const f16x8*)(Vsrc + jbeg + vko + 8);
        asm volatile("s_waitcnt vmcnt(0)" ::: "memory");
        *(f16x8*)&Vt[0][vch * 40 + vko] = va;
        *(f16x8*)&Vt[0][vch * 40 + vko + 8] = vb2;
    }
    __syncthreads();

    int cur = 0;
    for (int j0 = jbeg; j0 < jend; j0 += 32) {
        const bool pre = (j0 + 32) < jend;
        f16x8 va, vb2;
        if (pre) {
            stageK(cur ^ 1, j0 + 32);
            va = *(const f16x8*)(Vsrc + (j0 + 32) + vko);
            vb2 = *(const f16x8*)(Vsrc + (j0 + 32) + vko + 8);
        }
        // ---- QK^T: 16 k-slices over 256 ch ----
        f32x16 sacc;
#pragma unroll
        for (int r = 0; r < 16; r++) sacc[r] = 0.0f;
#pragma unroll
        for (int t = 0; t < 16; t++) {
            int pc = (2 * t + hi) ^ (i31 & 7);  // de-swizzle chunk
            f16x8 kf = *(const f16x8*)&Klds[cur][i31 * 256 + pc * 8];
            sacc = MFMA32F(kf, qf[t], sacc);
        }
        // ---- softmax (lane pair (l, l^32) shares query i31) ----
        float tm = sacc[0];
#pragma unroll
        for (int r = 1; r < 16; r++) tm = fmaxf(tm, sacc[r]);
        tm = fmaxf(tm, __shfl_xor(tm, 32));
        if (__any(tm - M > 8.0f)) {
            float newM = fmaxf(M, tm);
            float alpha = exp2f(M - newM);  // 0 on first tile
            Lsum *= alpha;
            float ar[16];
#pragma unroll
            for (int r = 0; r < 16; r++)
                ar[r] = __shfl(alpha, (r & 3) + 8 * (r >> 2) + 4 * hi);
#pragma unroll
            for (int ct = 0; ct < 8; ct++)
#pragma unroll
                for (int r = 0; r < 16; r++) acc[ct][r] *= ar[r];
            M = newM;
        }
        float p[16], ps = 0.0f;
#pragma unroll
        for (int r = 0; r < 16; r++) {
            p[r] = exp2f(sacc[r] - M);  // bounded by 2^8
            ps += p[r];
        }
        Lsum += ps;
        // pack quads: lane's quad q covers j = 8q + 4hi + 0..3
        uint32 Pq[4][2];
#pragma unroll
        for (int q = 0; q < 4; q++) {
            Pq[q][0] = pkf16(p[4 * q + 0], p[4 * q + 1]);
            Pq[q][1] = pkf16(p[4 * q + 2], p[4 * q + 3]);
        }
        // ---- PV: 2 k-instrs (j 0..15, 16..31) x 8 c-tiles ----
#pragma unroll
        for (int tp = 0; tp < 2; tp++) {
            uint32 x0 = Pq[2 * tp][0], y0 = Pq[2 * tp + 1][0];
            uint32 x1 = Pq[2 * tp][1], y1 = Pq[2 * tp + 1][1];
            asm volatile("v_permlane32_swap_b32 %0, %1" : "+v"(x0), "+v"(y0));
            asm volatile("v_permlane32_swap_b32 %0, %1" : "+v"(x1), "+v"(y1));
            union { uint32 u[4]; f16x8 v; } pa;
            pa.u[0] = x0;  // j +0,1
            pa.u[1] = x1;  // j +2,3
            pa.u[2] = y0;  // j +4,5
            pa.u[3] = y1;  // j +6,7
#pragma unroll
            for (int ct = 0; ct < 8; ct++) {
                f16x8 vf = *(const f16x8*)&Vt[cur][(ct * 32 + i31) * 40 + tp * 16 + hi * 8];
                acc[ct] = MFMA32F(pa.v, vf, acc[ct]);
            }
        }
        if (pre) {
            asm volatile("s_waitcnt vmcnt(0)" ::: "memory");
            *(f16x8*)&Vt[cur ^ 1][vch * 40 + vko] = va;
            *(f16x8*)&Vt[cur ^ 1][vch * 40 + vko + 8] = vb2;
        }
        __syncthreads();
        cur ^= 1;
    }
    float Lt = Lsum + __shfl_xor(Lsum, 32);
    float inv = 1.0f / Lt;
    float ivr[16];
#pragma unroll
    for (int r = 0; r < 16; r++)
        ivr[r] = __shfl(inv, (r & 3) + 8 * (r >> 2) + 4 * hi);
    const size_t sb = (size_t)(s * 4 + b);
    _Float16* Ob = Opart + (sb * 4096 + iwq) * 256;
#pragma unroll
    for (int ct = 0; ct < 8; ct++) {
#pragma unroll
        for (int r = 0; r < 16; r++) {
            int ir = (r & 3) + 8 * (r >> 2) + 4 * hi;
            Ob[(size_t)ir * 256 + ct * 32 + i31] = (_Float16)(acc[ct][r] * ivr[r]);
        }
    }
    if (l < 32) {
        float2 ml;
        ml.x = M;
        ml.y = Lt;
        ML[sb * 4096 + iwq + l] = ml;
    }
}

// ---------------------------------------------------------------------------
// Kernel 3b: combine 4 splits. grid (512, 4), block 256.
// ---------------------------------------------------------------------------
__global__ __launch_bounds__(256) void attn_combine(
    const _Float16* __restrict__ Opart, const float2* __restrict__ ML,
    _Float16* __restrict__ Rt) {
    const int b = blockIdx.y;
    const int i = blockIdx.x * 8 + (threadIdx.x >> 5);
    const int c0 = (threadIdx.x & 31) * 8;
    float m[4], lv[4];
#pragma unroll
    for (int s = 0; s < 4; s++) {
        float2 ml = ML[(size_t)(s * 4 + b) * 4096 + i];
        m[s] = ml.x;
        lv[s] = ml.y;
    }
    float Mmax = fmaxf(fmaxf(m[0], m[1]), fmaxf(m[2], m[3]));
    float w[4], denom = 0.0f;
#pragma unroll
    for (int s = 0; s < 4; s++) {
        w[s] = lv[s] * exp2f(m[s] - Mmax);
        denom += w[s];
    }
    float inv = 1.0f / denom;
    float o[8] = {0, 0, 0, 0, 0, 0, 0, 0};
#pragma unroll
    for (int s = 0; s < 4; s++) {
        float ws = w[s] * inv;
        f16x8 v = *(const f16x8*)(Opart + ((size_t)(s * 4 + b) * 4096 + i) * 256 + c0);
#pragma unroll
        for (int e = 0; e < 8; e++) o[e] += ws * (float)v[e];
    }
    f16x8 r;
#pragma unroll
    for (int e = 0; e < 8; e++) r[e] = (_Float16)o[e];
    *(f16x8*)(Rt + ((size_t)b * 4096 + i) * 256 + c0) = r;
}

// ---------------------------------------------------------------------------
// Kernel 4: out[o,i] = wo[o,:]·Rt[i,:] + bo[o], fp32 out [C][N]. f16 MFMA.
// grid (256, B), block 256
// ---------------------------------------------------------------------------
__global__ __launch_bounds__(256) void out_proj(
    const _Float16* __restrict__ wob, const _Float16* __restrict__ Rt,
    const float* __restrict__ bo, float* __restrict__ Out) {
    const int b = blockIdx.y;
    const int m0 = (blockIdx.x & 3) * 64;
    const int n0 = (blockIdx.x >> 2) * 64;
    const int l = threadIdx.x & 63, wv = threadIdx.x >> 6;
    const int g = l >> 4, l15 = l & 15;
    const _Float16* Bp = Rt + (size_t)b * 4096 * 256;
    float* Ob = Out + (size_t)b * 256 * 4096;
    const int mrow = m0 + wv * 16 + l15;

    f32x4 acc[4] = {{0, 0, 0, 0}, {0, 0, 0, 0}, {0, 0, 0, 0}, {0, 0, 0, 0}};
#pragma unroll
    for (int kk = 0; kk < 8; kk++) {
        f16x8 a = *(const f16x8*)(wob + (size_t)mrow * 256 + kk * 32 + g * 8);
#pragma unroll
        for (int nt = 0; nt < 4; nt++) {
            f16x8 bfr = *(const f16x8*)(Bp + (size_t)(n0 + nt * 16 + l15) * 256 + kk * 32 + g * 8);
            acc[nt] = MFMA16F(a, bfr, acc[nt]);
        }
    }
#pragma unroll
    for (int nt = 0; nt < 4; nt++) {
#pragma unroll
        for (int r = 0; r < 4; r++) {
            int mr = m0 + wv * 16 + g * 4 + r;
            Ob[(size_t)mr * 4096 + n0 + nt * 16 + l15] = acc[nt][r] + bo[mr];
        }
    }
}

// ---------------------------------------------------------------------------
extern "C" void kernel_launch(void* const* d_in, const int* in_sizes, int n_in,
                              void* d_out, int out_size, void* d_ws, size_t ws_size,
                              hipStream_t stream) {
    const float* Fc = (const float*)d_in[0];
    const float* Fs = (const float*)d_in[1];
    const float* wf = (const float*)d_in[2];
    const float* bf_ = (const float*)d_in[3];
    const float* wg = (const float*)d_in[4];
    const float* bg = (const float*)d_in[5];
    const float* wh = (const float*)d_in[6];
    const float* bh = (const float*)d_in[7];
    const float* wo = (const float*)d_in[8];
    const float* bo = (const float*)d_in[9];
    float* Out = (float*)d_out;

    char* ws = (char*)d_ws;
    const size_t SZ = (size_t)4 * 4096 * 256 * 2;  // 8 MB per [B][4096][256] f16
    _Float16* QFp = (_Float16*)(ws + 0 * SZ);
    _Float16* KFp = (_Float16*)(ws + 1 * SZ);
    _Float16* VFp = (_Float16*)(ws + 2 * SZ);
    _Float16* Xc  = (_Float16*)(ws + 3 * SZ);
    _Float16* Xs  = (_Float16*)(ws + 4 * SZ);
    _Float16* Opart = (_Float16*)(ws + 5 * SZ);  // [16][4096][256] f16 = 32 MB
    char* wsw = ws + 9 * SZ;
    _Float16* wfh = (_Float16*)(wsw + 0 * 131072);
    _Float16* wfl = (_Float16*)(wsw + 1 * 131072);
    _Float16* wgh = (_Float16*)(wsw + 2 * 131072);
    _Float16* wgl = (_Float16*)(wsw + 3 * 131072);
    _Float16* whb = (_Float16*)(wsw + 4 * 131072);
    _Float16* wob = (_Float16*)(wsw + 5 * 131072);
    float2* ML = (float2*)(wsw + 6 * 131072);  // 16*4096*8 = 512 KB
    _Float16* Rt = QFp;  // alias: Q dead once attn_split completes

    transpose_f16<<<dim3(64, 4, 8), 256, 0, stream>>>(Fc, Fs, Xc, Xs);
    convert_weights<<<dim3(256), 256, 0, stream>>>(wf, wg, wh, wo, wfh, wfl, wgh, wgl, whb, wob);
    proj_qk<<<dim3(256, 8), 256, 0, stream>>>(Xc, Xs, wfh, wfl, wgh, wgl, bf_, bg, QFp, KFp);
    proj_v<<<dim3(256, 4), 256, 0, stream>>>(Xs, whb, bh, VFp);
    attn_split<<<dim3(256), 512, 0, stream>>>(QFp, KFp, VFp, Opart, ML);
    attn_combine<<<dim3(512, 4), 256, 0, stream>>>(Opart, ML, Rt);
    out_proj<<<dim3(256, 4), 256, 0, stream>>>(wob, Rt, bo, Out);
}